// Round 1
// baseline (1812.439 us; speedup 1.0000x reference)
//
#include <hip/hip_runtime.h>
#include <cstdint>
#include <cstddef>

#define B_DIM 64
#define S_DIM 2048
#define E_DIM 1024
#define H_DIM 512
#define BM    64
#define BK    32
#define NSTEP (E_DIM / BK)   // 32
#define APAD  40             // row pad (bf16 elems): bank = r*20 mod 32 -> 2-way (free)
#define CTX_N (B_DIM * E_DIM)

typedef unsigned short u16;
typedef unsigned int   u32;
typedef short  s16x8 __attribute__((ext_vector_type(8)));
typedef __bf16 bf16x8 __attribute__((ext_vector_type(8)));
typedef float  f32x4 __attribute__((ext_vector_type(4)));

__device__ __forceinline__ u16 f2bf(float f){
  u32 u = __float_as_uint(f);
  u += 0x7FFFu + ((u >> 16) & 1u);   // RNE
  return (u16)(u >> 16);
}

// ---------------- K0a: WhT[h][e] = bf16(Wh[e][h]) ----------------
__global__ __launch_bounds__(256) void k_transpose(const float* __restrict__ Wh,
                                                   u16* __restrict__ WhT){
  int idx = blockIdx.x * 256 + threadIdx.x;       // 0 .. 524287
  int h = idx >> 10, e = idx & (E_DIM - 1);
  WhT[idx] = f2bf(Wh[e * H_DIM + h]);             // coalesced write, strided read (L2)
}

// ---------------- K0b: pd[b][h] = dec[b,:] @ Wd ----------------
__global__ __launch_bounds__(256) void k_projdec(const float* __restrict__ dec,
                                                 const float* __restrict__ Wd,
                                                 float* __restrict__ pd){
  __shared__ float dl[H_DIM];
  int b = blockIdx.x, tid = threadIdx.x;
  dl[tid]       = dec[b * H_DIM + tid];
  dl[tid + 256] = dec[b * H_DIM + tid + 256];
  __syncthreads();
  for (int hh = 0; hh < 2; ++hh){
    int h = tid + hh * 256;
    float acc = 0.f;
    #pragma unroll 8
    for (int k = 0; k < H_DIM; ++k) acc += dl[k] * Wd[k * H_DIM + h];
    pd[b * H_DIM + h] = acc;
  }
}

// ---------------- K1: fused enc@Wh + pd + tanh + dot(v) + mask -> scores ----------------
// grid 2048 = 64 b x 32 s-chunks, 512 threads (8 waves: ws=wid>>2 over s, wh=wid&3 over h)
__global__ __launch_bounds__(512, 2) void k_score(
    const float* __restrict__ enc, const u16* __restrict__ WhT,
    const float* __restrict__ pd, const float* __restrict__ vvec,
    const int* __restrict__ mask, float* __restrict__ scores)
{
  __shared__ u16 As[BM * APAD];          // [64][40] bf16, single buffer (reg double-buffer)
  __shared__ u16 Bs[H_DIM * APAD];       // [512][40] bf16
  __shared__ float pdv[H_DIM];
  __shared__ float vv[H_DIM];
  __shared__ float scp[4 * BM];          // [wh][s_local]

  const int tid = threadIdx.x;
  const int bx  = blockIdx.x;
  const int b   = bx >> 5;
  const int s0  = (bx & 31) * BM;
  const float* encB = enc + ((size_t)b * S_DIM + s0) * E_DIM;

  pdv[tid] = pd[b * H_DIM + tid & 511 ? b * H_DIM + tid : b * H_DIM + tid]; // (tid<512 always)
  pdv[tid] = pd[b * H_DIM + tid];
  vv[tid]  = vvec[tid];

  const int lane = tid & 63;
  const int wid  = tid >> 6;
  const int ws   = wid >> 2, wh = wid & 3;
  const int l15  = lane & 15, l4 = lane >> 4;
  const int ar   = tid >> 3, ac4 = tid & 7;   // A staging: row, float4-col

  f32x4 acc[2][8] = {};

  float4 aReg;
  uint4  bReg[4];

  // prologue: load + write k-step 0
  aReg = *reinterpret_cast<const float4*>(encB + (size_t)ar * E_DIM + ac4 * 4);
  {
    const uint4* bp = reinterpret_cast<const uint4*>(WhT + (size_t)tid * E_DIM);
    bReg[0] = bp[0]; bReg[1] = bp[1]; bReg[2] = bp[2]; bReg[3] = bp[3];
  }
  {
    u32 lo = (u32)f2bf(aReg.x) | ((u32)f2bf(aReg.y) << 16);
    u32 hi = (u32)f2bf(aReg.z) | ((u32)f2bf(aReg.w) << 16);
    *reinterpret_cast<uint2*>(&As[ar * APAD + ac4 * 4]) = make_uint2(lo, hi);
    uint4* bw = reinterpret_cast<uint4*>(&Bs[tid * APAD]);
    bw[0] = bReg[0]; bw[1] = bReg[1]; bw[2] = bReg[2]; bw[3] = bReg[3];
  }

  const u16* Ab = &As[(ws * 32 + l15) * APAD + l4 * 8];
  const u16* Bb = &Bs[(wh * 128 + l15) * APAD + l4 * 8];

  for (int t = 0; t < NSTEP; ++t){
    if (t + 1 < NSTEP){   // issue next-step global loads early (latency hides under MFMA)
      aReg = *reinterpret_cast<const float4*>(encB + (size_t)ar * E_DIM + (t + 1) * BK + ac4 * 4);
      const uint4* bp = reinterpret_cast<const uint4*>(WhT + (size_t)tid * E_DIM + (t + 1) * BK);
      bReg[0] = bp[0]; bReg[1] = bp[1]; bReg[2] = bp[2]; bReg[3] = bp[3];
    }
    __syncthreads();      // staged data for step t visible
    s16x8 afr[2], bfr[8];
    #pragma unroll
    for (int si = 0; si < 2; ++si) afr[si] = *reinterpret_cast<const s16x8*>(Ab + si * 16 * APAD);
    #pragma unroll
    for (int hi = 0; hi < 8; ++hi) bfr[hi] = *reinterpret_cast<const s16x8*>(Bb + hi * 16 * APAD);
    #pragma unroll
    for (int si = 0; si < 2; ++si)
      #pragma unroll
      for (int hi = 0; hi < 8; ++hi)
        acc[si][hi] = __builtin_amdgcn_mfma_f32_16x16x32_bf16(
            __builtin_bit_cast(bf16x8, afr[si]),
            __builtin_bit_cast(bf16x8, bfr[hi]),
            acc[si][hi], 0, 0, 0);
    __syncthreads();      // all waves done reading step t
    if (t + 1 < NSTEP){   // write step t+1 into (single) LDS buffers
      u32 lo = (u32)f2bf(aReg.x) | ((u32)f2bf(aReg.y) << 16);
      u32 hi = (u32)f2bf(aReg.z) | ((u32)f2bf(aReg.w) << 16);
      *reinterpret_cast<uint2*>(&As[ar * APAD + ac4 * 4]) = make_uint2(lo, hi);
      uint4* bw = reinterpret_cast<uint4*>(&Bs[tid * APAD]);
      bw[0] = bReg[0]; bw[1] = bReg[1]; bw[2] = bReg[2]; bw[3] = bReg[3];
    }
  }

  // epilogue: energy = tanh(acc + pd[h]); partial score += energy * v[h]
  float part[8];
  #pragma unroll
  for (int j = 0; j < 8; ++j) part[j] = 0.f;
  #pragma unroll
  for (int hi = 0; hi < 8; ++hi){
    int h = wh * 128 + hi * 16 + l15;
    float pdh = pdv[h], vh = vv[h];
    #pragma unroll
    for (int si = 0; si < 2; ++si)
      #pragma unroll
      for (int r = 0; r < 4; ++r){
        float x = acc[si][hi][r] + pdh;
        float e = __expf(2.f * x);          // overflow-safe: x>>0 -> e=inf -> th=1
        float th = 1.f - 2.f / (e + 1.f);
        part[si * 4 + r] += th * vh;
      }
  }
  // reduce over the 16 h-columns held by the 16-lane group
  #pragma unroll
  for (int off = 1; off < 16; off <<= 1)
    #pragma unroll
    for (int j = 0; j < 8; ++j)
      part[j] += __shfl_xor(part[j], off, 64);
  if (l15 == 0){
    #pragma unroll
    for (int j = 0; j < 8; ++j){
      int si = j >> 2, r = j & 3;
      scp[wh * BM + ws * 32 + si * 16 + l4 * 4 + r] = part[j];
    }
  }
  __syncthreads();
  if (tid < BM){
    float sc = scp[tid] + scp[BM + tid] + scp[2 * BM + tid] + scp[3 * BM + tid];
    int mk = mask[b * S_DIM + s0 + tid];
    scores[(size_t)b * S_DIM + s0 + tid] = (mk == 0) ? -10000.0f : sc;
  }
}

// ---------------- K2: row softmax -> attn (d_out + CTX_N) ----------------
__global__ __launch_bounds__(512) void k_softmax(const float* __restrict__ scores,
                                                 float* __restrict__ attn){
  __shared__ float red[8];
  int b = blockIdx.x, tid = threadIdx.x;
  float4 v = reinterpret_cast<const float4*>(scores + (size_t)b * S_DIM)[tid];
  float m = fmaxf(fmaxf(v.x, v.y), fmaxf(v.z, v.w));
  #pragma unroll
  for (int off = 32; off; off >>= 1) m = fmaxf(m, __shfl_xor(m, off, 64));
  if ((tid & 63) == 0) red[tid >> 6] = m;
  __syncthreads();
  m = red[0];
  #pragma unroll
  for (int i = 1; i < 8; ++i) m = fmaxf(m, red[i]);
  float e0 = __expf(v.x - m), e1 = __expf(v.y - m), e2 = __expf(v.z - m), e3 = __expf(v.w - m);
  float s = e0 + e1 + e2 + e3;
  #pragma unroll
  for (int off = 32; off; off >>= 1) s += __shfl_xor(s, off, 64);
  __syncthreads();
  if ((tid & 63) == 0) red[tid >> 6] = s;
  __syncthreads();
  s = red[0] + red[1] + red[2] + red[3] + red[4] + red[5] + red[6] + red[7];
  float inv = 1.f / s;
  float4 o; o.x = e0 * inv; o.y = e1 * inv; o.z = e2 * inv; o.w = e3 * inv;
  reinterpret_cast<float4*>(attn + (size_t)b * S_DIM)[tid] = o;
}

// ---------------- K3: context[b][e] += sum_s attn*enc (memset'd, atomic) ----------------
__global__ __launch_bounds__(256) void k_ctx(const float* __restrict__ enc,
                                             const float* __restrict__ attn,
                                             float* __restrict__ ctx){
  int b = blockIdx.x >> 3, chunk = blockIdx.x & 7;
  int tid = threadIdx.x;
  __shared__ float w[256];
  w[tid] = attn[(size_t)b * S_DIM + chunk * 256 + tid];
  __syncthreads();
  const float4* e4 = reinterpret_cast<const float4*>(enc + ((size_t)b * S_DIM + chunk * 256) * E_DIM) + tid;
  float4 acc; acc.x = acc.y = acc.z = acc.w = 0.f;
  #pragma unroll 4
  for (int i = 0; i < 256; ++i){
    float4 ev = e4[(size_t)i * 256];
    float ww = w[i];
    acc.x += ww * ev.x; acc.y += ww * ev.y; acc.z += ww * ev.z; acc.w += ww * ev.w;
  }
  float* o = ctx + (size_t)b * E_DIM + tid * 4;
  atomicAdd(o + 0, acc.x); atomicAdd(o + 1, acc.y);
  atomicAdd(o + 2, acc.z); atomicAdd(o + 3, acc.w);
}

extern "C" void kernel_launch(void* const* d_in, const int* in_sizes, int n_in,
                              void* d_out, int out_size, void* d_ws, size_t ws_size,
                              hipStream_t stream){
  const float* dec  = (const float*)d_in[0];
  const float* enc  = (const float*)d_in[1];
  const int*   mask = (const int*)  d_in[2];
  const float* Wh   = (const float*)d_in[3];
  const float* Wd   = (const float*)d_in[4];
  const float* v    = (const float*)d_in[5];
  float* out  = (float*)d_out;
  float* ctx  = out;            // 64*1024
  float* attn = out + CTX_N;    // 64*2048

  // ws layout: WhT bf16 [0,1MB) | pd f32 [1MB,1.125MB) | scores f32 [1.125MB,1.625MB)
  u16*   WhT    = (u16*)d_ws;
  float* pd     = (float*)((char*)d_ws + 1048576);
  float* scores = (float*)((char*)d_ws + 1179648);

  hipMemsetAsync(ctx, 0, CTX_N * sizeof(float), stream);
  k_transpose<<<(H_DIM * E_DIM) / 256, 256, 0, stream>>>(Wh, WhT);
  k_projdec  <<<B_DIM, 256, 0, stream>>>(dec, Wd, pd);
  k_score    <<<B_DIM * (S_DIM / BM), 512, 0, stream>>>(enc, WhT, pd, v, mask, scores);
  k_softmax  <<<B_DIM, 512, 0, stream>>>(scores, attn);
  k_ctx      <<<B_DIM * 8, 256, 0, stream>>>(enc, attn, ctx);
}